// Round 10
// baseline (330.421 us; speedup 1.0000x reference)
//
#include <hip/hip_runtime.h>
#include <hip/hip_bf16.h>
#include <math.h>

#define NUM_CLUSTERS 16
#define HIDDEN 1024
#define BOT 128
#define NTOK 65536

typedef __attribute__((ext_vector_type(8))) short bf16x8;
typedef __attribute__((ext_vector_type(4))) float f32x4;

typedef __attribute__((address_space(3))) unsigned int lds_u32;
typedef const __attribute__((address_space(1))) unsigned int glb_u32;

__device__ __forceinline__ void gload16(const void* g, void* l) {
  __builtin_amdgcn_global_load_lds((glb_u32*)g, (lds_u32*)l, 16, 0, 0);
}

__device__ __forceinline__ unsigned short f2bf(float x) {
  union { float f; unsigned u; } v; v.f = x;
  unsigned r = v.u + 0x7fffu + ((v.u >> 16) & 1u);
  return (unsigned short)(r >> 16);
}

__device__ __forceinline__ bf16x8 pack8(float4 a, float4 b) {
  bf16x8 r;
  r[0] = (short)f2bf(a.x); r[1] = (short)f2bf(a.y);
  r[2] = (short)f2bf(a.z); r[3] = (short)f2bf(a.w);
  r[4] = (short)f2bf(b.x); r[5] = (short)f2bf(b.y);
  r[6] = (short)f2bf(b.z); r[7] = (short)f2bf(b.w);
  return r;
}

// short-index swizzle: XOR short-idx bits 3..5 with (row&7) -> 16B-chunk spread
#define SWZS(row, sidx) ((sidx) ^ (((row) & 7) << 3))
// f32-index swizzle (16B granule)
#define SW4(row, fidx) ((fidx) ^ (((row) & 7) << 2))

#define SCB() __builtin_amdgcn_sched_barrier(0)
#define VMW(n)                                          \
  do {                                                  \
    SCB();                                              \
    asm volatile("s_waitcnt vmcnt(" #n ")" ::: "memory"); \
    SCB();                                              \
  } while (0)
#define SBAR()                                  \
  do {                                          \
    SCB();                                      \
    __builtin_amdgcn_s_barrier();               \
    SCB();                                      \
  } while (0)
#define LGKM0() asm volatile("s_waitcnt lgkmcnt(0)" ::: "memory")

// bijective XCD-chunk swizzle (m204)
__device__ __forceinline__ int xcd_swz(int bid, int nwg) {
  const int nx = 8;
  int q = nwg / nx, r = nwg % nx;
  int xcd = bid % nx, idx = bid / nx;
  int b = (xcd < r) ? xcd * (q + 1) : r * (q + 1) + (xcd - r) * q;
  return b + idx;
}

// ---------------- prep kernels ----------------

__global__ void k_zero(int* p) {
  if (threadIdx.x < 64) p[threadIdx.x] = 0;
}

__global__ void k_hist(const int* __restrict__ ids, int* __restrict__ counts) {
  __shared__ int lh[NUM_CLUSTERS];
  if (threadIdx.x < NUM_CLUSTERS) lh[threadIdx.x] = 0;
  __syncthreads();
  int i = blockIdx.x * blockDim.x + threadIdx.x;
  int stride = gridDim.x * blockDim.x;
  for (; i < NTOK; i += stride) atomicAdd(&lh[ids[i]], 1);
  __syncthreads();
  if (threadIdx.x < NUM_CLUSTERS) atomicAdd(&counts[threadIdx.x], lh[threadIdx.x]);
}

__global__ void k_scan(const int* __restrict__ counts, int* __restrict__ offsets,
                       int* __restrict__ cursor) {
  if (threadIdx.x == 0 && blockIdx.x == 0) {
    int s = 0;
    for (int c = 0; c < NUM_CLUSTERS; ++c) {
      offsets[c] = s; cursor[c] = s; s += counts[c];
    }
    offsets[NUM_CLUSTERS] = s;
  }
}

__global__ void k_scatter(const int* __restrict__ ids, int* cursor,
                          int* __restrict__ perm) {
  __shared__ int lh[NUM_CLUSTERS], lbase[NUM_CLUSTERS];
  const int tid = threadIdx.x;
  if (tid < NUM_CLUSTERS) lh[tid] = 0;
  __syncthreads();
  const int i = blockIdx.x * 256 + tid;
  const int cc = ids[i];
  const int r = atomicAdd(&lh[cc], 1);
  __syncthreads();
  if (tid < NUM_CLUSTERS) lbase[tid] = atomicAdd(&cursor[tid], lh[tid]);
  __syncthreads();
  perm[lbase[cc] + r] = i;
}

// W1 [16][1024][128] -> per-(c,ks) 16KB swizzled images of W1^T [n=128][k=64]
__global__ void k_w1til(const float* __restrict__ W1, unsigned short* __restrict__ outw) {
  const int id = blockIdx.x * 256 + threadIdx.x;   // 262144 total
  const int c  = id >> 14;
  const int ks = (id >> 10) & 15;
  const int q  = id & 1023;
  const int o  = q << 4;                 // stored byte offset in image
  const int row = o >> 7;                // n
  const int lb  = (o & 127) ^ ((row & 7) << 4);
  const int k0  = ks * 64 + (lb >> 1);   // 8 consecutive k
  const float* src = W1 + ((size_t)c * HIDDEN + k0) * BOT + row;
  unsigned short v[8];
  #pragma unroll
  for (int j = 0; j < 8; ++j) v[j] = f2bf(src[(size_t)j * BOT]);
  *(uint4*)((char*)outw + ((size_t)(c * 16 + ks)) * 16384 + o) = *(const uint4*)v;
}

// W2 [16][128][1024] -> fragment-linear lin layout for barrier-free gemm2:
// outw[((c*16 + nc)*16 + kk*4 + nf)*512 + l*8 + i] =
//   bf16(W2[c][kk*32 + (l>>4)*8 + i][nc*64 + nf*16 + (l&15)])
__global__ void k_w2lin(const float* __restrict__ W2, unsigned short* __restrict__ outw) {
  const int id = blockIdx.x * 256 + threadIdx.x;   // 262144 total
  const int c   = id >> 14;
  const int rem = id & 16383;
  const int fg  = rem >> 6;            // nc*16 + kk*4 + nf
  const int l   = rem & 63;
  const int nc  = fg >> 4, kk = (fg >> 2) & 3, nf = fg & 3;
  const int n   = nc * 64 + nf * 16 + (l & 15);
  const int k0  = kk * 32 + (l >> 4) * 8;
  const float* src = W2 + ((size_t)c * BOT + k0) * HIDDEN + n;
  unsigned short v[8];
  #pragma unroll
  for (int j = 0; j < 8; ++j) v[j] = f2bf(src[(size_t)j * HIDDEN]);
  *(uint4*)(outw + (size_t)id * 8) = *(const uint4*)v;
}

// W2 [16][128][1024] -> per-(c,nc) 16KB swizzled images (FALLBACK path only)
__global__ void k_w2til(const float* __restrict__ W2, unsigned short* __restrict__ outw) {
  const int id = blockIdx.x * 256 + threadIdx.x;   // 262144 total
  const int c  = id >> 14;
  const int nc = (id >> 10) & 15;
  const int q  = id & 1023;
  const int o  = q << 4;
  const int row = o >> 8;                // n' 0..63
  const int lb  = (o & 255) ^ ((row & 7) << 4);
  const int b0  = lb >> 1;               // 8 consecutive b
  const int n   = nc * 64 + row;
  const float* src = W2 + ((size_t)c * BOT + b0) * HIDDEN + n;
  unsigned short v[8];
  #pragma unroll
  for (int j = 0; j < 8; ++j) v[j] = f2bf(src[(size_t)j * HIDDEN]);
  *(uint4*)((char*)outw + ((size_t)(c * 16 + nc)) * 16384 + o) = *(const uint4*)v;
}

// ---- common tile locator: TM tokens per tile ----
__device__ __forceinline__ bool locate(const int* offsets, int bid, int TMv,
                                       int& c, int& base, int& nvalid) {
  int t = bid;
  for (c = 0; c < NUM_CLUSTERS; ++c) {
    int cnt = offsets[c + 1] - offsets[c];
    int nt = (cnt + TMv - 1) / TMv;
    if (t < nt) {
      base = offsets[c] + t * TMv;
      nvalid = min(TMv, offsets[c + 1] - base);
      return true;
    }
    t -= nt;
  }
  return false;
}

// ---------------- pass 1: mid = gelu(h@W1 + b1) (unchanged from R9) ----------------
__global__ __launch_bounds__(512, 6) void k_gemm1(
    const float* __restrict__ h, const float* __restrict__ b1g,
    const unsigned short* __restrict__ W1til, const int* __restrict__ offsets,
    const int* __restrict__ perm, unsigned short* __restrict__ midg) {

  __shared__ __align__(16) unsigned short sA[2][4096];
  __shared__ __align__(16) unsigned short sB[2][8192];
  __shared__ int sTok[64];

  const int tid = threadIdx.x;
  const int l = tid & 63, w = tid >> 6;
  const int lr = l & 15, lg = l >> 4;
  const int wr = w >> 2, wc = w & 3;
  const int row = tid >> 3, o8 = tid & 7;

  const int nwg = NTOK / 64 + NUM_CLUSTERS;
  int c, base, nvalid;
  if (!locate(offsets, xcd_swz(blockIdx.x, nwg), 64, c, base, nvalid)) return;

  if (tid < 64) sTok[tid] = perm[base + min(tid, nvalid - 1)];
  LGKM0();
  SBAR();

  const unsigned short* w1base = W1til + (size_t)c * 16 * 8192;
  const float* hrow = h + (long)sTok[row] * HIDDEN + o8 * 8;

  float4 vaA[2], vaB[2];
  vaA[0] = *(const float4*)(hrow);       vaA[1] = *(const float4*)(hrow + 4);
  SCB();
  gload16(w1base + tid * 8, &sB[0][tid * 8]);
  gload16(w1base + 4096 + tid * 8, &sB[0][4096 + tid * 8]);
  SCB();
  vaB[0] = *(const float4*)(hrow + 64);  vaB[1] = *(const float4*)(hrow + 68);
  SCB();
  *(bf16x8*)&sA[0][SWZS(row, row * 64 + o8 * 8)] = pack8(vaA[0], vaA[1]);
  LGKM0();
  VMW(2);
  SBAR();

  f32x4 acc[2][2];
  #pragma unroll
  for (int i = 0; i < 2; ++i)
    #pragma unroll
    for (int j = 0; j < 2; ++j) { f32x4 z = {0.f, 0.f, 0.f, 0.f}; acc[i][j] = z; }

#define G1_MFMA(CUR)                                                          \
  do {                                                                        \
    _Pragma("unroll")                                                         \
    for (int kk = 0; kk < 2; ++kk) {                                          \
      bf16x8 af[2], bfr[2];                                                   \
      _Pragma("unroll")                                                       \
      for (int mf = 0; mf < 2; ++mf) {                                        \
        const int m = wr * 32 + mf * 16 + lr;                                 \
        af[mf] = *(const bf16x8*)&sA[CUR][SWZS(m, m * 64 + kk * 32 + lg * 8)];\
      }                                                                       \
      _Pragma("unroll")                                                       \
      for (int nf = 0; nf < 2; ++nf) {                                        \
        const int rn = wc * 32 + nf * 16 + lr;                                \
        bfr[nf] = *(const bf16x8*)&sB[CUR][SWZS(rn, rn * 64 + kk * 32 + lg * 8)]; \
      }                                                                       \
      _Pragma("unroll")                                                       \
      for (int mf = 0; mf < 2; ++mf)                                          \
        _Pragma("unroll")                                                     \
        for (int nf = 0; nf < 2; ++nf)                                        \
          acc[mf][nf] = __builtin_amdgcn_mfma_f32_16x16x32_bf16(              \
              af[mf], bfr[nf], acc[mf][nf], 0, 0, 0);                         \
    }                                                                         \
  } while (0)

  #pragma unroll
  for (int t = 0; t < 16; ++t) {
    const int cur = t & 1;
    if (t < 15) {
      const unsigned short* w1s = w1base + (t + 1) * 8192;
      gload16(w1s + tid * 8, &sB[cur ^ 1][tid * 8]);
      gload16(w1s + 4096 + tid * 8, &sB[cur ^ 1][4096 + tid * 8]);
      SCB();
    }
    if (t < 14) {
      if (t & 1) {
        vaB[0] = *(const float4*)(hrow + (t + 2) * 64);
        vaB[1] = *(const float4*)(hrow + (t + 2) * 64 + 4);
      } else {
        vaA[0] = *(const float4*)(hrow + (t + 2) * 64);
        vaA[1] = *(const float4*)(hrow + (t + 2) * 64 + 4);
      }
      SCB();
    }
    G1_MFMA(cur);
    if (t < 15) {
      const float4* src = ((t + 1) & 1) ? vaB : vaA;
      *(bf16x8*)&sA[cur ^ 1][SWZS(row, row * 64 + o8 * 8)] = pack8(src[0], src[1]);
      if (t < 14) { VMW(2); } else { VMW(0); }
      LGKM0();
      SBAR();
    }
  }
#undef G1_MFMA

  float b1v[2];
  #pragma unroll
  for (int nf = 0; nf < 2; ++nf) b1v[nf] = b1g[c * BOT + wc * 32 + nf * 16 + lr];
  #pragma unroll
  for (int mf = 0; mf < 2; ++mf) {
    #pragma unroll
    for (int nf = 0; nf < 2; ++nf) {
      #pragma unroll
      for (int r = 0; r < 4; ++r) {
        float x = acc[mf][nf][r] + b1v[nf];
        float g = 0.5f * x * (1.0f + erff(x * 0.70710678118654752f));
        const int m = wr * 32 + mf * 16 + lg * 4 + r;
        if (m < nvalid) {
          const int n = wc * 32 + nf * 16 + lr;
          midg[(size_t)(base + m) * BOT + n] = f2bf(g);
        }
      }
    }
  }
}

// ---------------- pass 2: out = h + mid@W2 + b2 — BARRIER-FREE ----------------
// 256 threads = 4 independent waves; each wave owns 16 tokens x 1024 cols.
// A (mid rows) held in registers (16 VGPR); B-fragments read directly from
// fragment-linear W2lin (1KB coalesced wave reads, L2-hot). Epilogue via
// wave-private 4KB LDS f32 tile (no cross-wave sharing -> zero barriers).

__global__ __launch_bounds__(256, 5) void k_gemm2(
    const float* __restrict__ h, const float* __restrict__ b2g,
    const unsigned short* __restrict__ W2lin, const int* __restrict__ offsets,
    const int* __restrict__ perm, const unsigned short* __restrict__ midg,
    float* __restrict__ out) {

  __shared__ __align__(16) float sOut[4 * 1024];   // 4 waves x 16x64 f32
  __shared__ int sTok[64];

  const int tid = threadIdx.x;
  const int l = tid & 63, w = tid >> 6;
  const int lr = l & 15, lg = l >> 4;

  const int nwg = NTOK / 64 + NUM_CLUSTERS;
  int c, base, nvalid;
  if (!locate(offsets, xcd_swz(blockIdx.x, nwg), 64, c, base, nvalid)) return;

  if (tid < 64) sTok[tid] = perm[base + min(tid, nvalid - 1)];
  __syncthreads();   // only block-wide sync in the kernel

  // A fragments: wave w's 16 mid rows, K=128 -> 4 frags of bf16x8 per lane
  const long amrow = (long)(base + min(w * 16 + lr, nvalid - 1)) * BOT;
  bf16x8 ma[4];
  #pragma unroll
  for (int kk = 0; kk < 4; ++kk)
    ma[kk] = *(const bf16x8*)(midg + amrow + kk * 32 + lg * 8);

  const unsigned short* wlin = W2lin + (size_t)c * 131072;

  // epilogue roles: lane covers row (l>>2), col-quarter (l&3) of wave tile
  const int er = l >> 2, ecg = l & 3;
  const int erow = w * 16 + er;
  const bool evalid = erow < nvalid;
  const long etok = (long)sTok[erow] * HIDDEN;
  const float* hrow = h + etok;
  float* orow = out + etok;
  float* sW = sOut + w * 1024;
  const float* b2c = b2g + c * HIDDEN;

  for (int nc = 0; nc < 16; ++nc) {
    const unsigned short* fbp = wlin + nc * 8192;

    f32x4 acc[4];
    #pragma unroll
    for (int i = 0; i < 4; ++i) { f32x4 z = {0.f, 0.f, 0.f, 0.f}; acc[i] = z; }

    #pragma unroll
    for (int kk = 0; kk < 4; ++kk) {
      #pragma unroll
      for (int nf = 0; nf < 4; ++nf) {
        const bf16x8 bf = *(const bf16x8*)(fbp + (kk * 4 + nf) * 512 + l * 8);
        acc[nf] = __builtin_amdgcn_mfma_f32_16x16x32_bf16(ma[kk], bf, acc[nf], 0, 0, 0);
      }
    }

    // residual/bias prefetch (compiler overlaps with LDS roundtrip)
    float4 hv[4], bv[4];
    #pragma unroll
    for (int j = 0; j < 4; ++j) {
      hv[j] = *(const float4*)(hrow + nc * 64 + ecg * 16 + j * 4);
      bv[j] = *(const float4*)(b2c + nc * 64 + ecg * 16 + j * 4);
    }

    // acc -> wave-private LDS f32 tile (swizzled; 2-way banks on write)
    #pragma unroll
    for (int nf = 0; nf < 4; ++nf) {
      #pragma unroll
      for (int r = 0; r < 4; ++r) {
        const int m = lg * 4 + r;
        const int n = nf * 16 + lr;
        sW[SW4(m, m * 64 + n)] = acc[nf][r];
      }
    }
    // same-wave readback: compiler inserts lgkmcnt; no barrier needed
    if (evalid) {
      #pragma unroll
      for (int j = 0; j < 4; ++j) {
        const int fo = er * 64 + ecg * 16 + j * 4;
        const float4 y = *(const float4*)&sW[SW4(er, fo)];
        float4 o;
        o.x = y.x + hv[j].x + bv[j].x;
        o.y = y.y + hv[j].y + bv[j].y;
        o.z = y.z + hv[j].z + bv[j].z;
        o.w = y.w + hv[j].w + bv[j].w;
        *(float4*)(orow + nc * 64 + ecg * 16 + j * 4) = o;
      }
    }
  }
}

// ---------------- fallback fused kernel (ws too small): TM=128 ----------------
#define FSWZ(row, sidx) ((sidx) ^ (((row) & 7) << 3))

__global__ __launch_bounds__(256, 2) void k_fused(
    const float* __restrict__ h, const float* __restrict__ b1g,
    const float* __restrict__ b2g, const unsigned short* __restrict__ W1til,
    const unsigned short* __restrict__ W2til, const int* __restrict__ offsets,
    const int* __restrict__ perm, float* __restrict__ out) {

  __shared__ __align__(16) unsigned short sAB[16384];
  __shared__ __align__(16) unsigned short sMid[16384];
  __shared__ int sTok[128];

  const int tid = threadIdx.x;
  const int l = tid & 63, w = tid >> 6;
  const int wr = w >> 1, wc = w & 1;
  const int lr = l & 15, lg = l >> 4;

  int c, base, nvalid;
  if (!locate(offsets, blockIdx.x, 128, c, base, nvalid)) return;

  if (tid < 128) sTok[tid] = perm[base + min(tid, nvalid - 1)];
  __syncthreads();

  const unsigned short* w1base = W1til + (size_t)c * 16 * 8192;
  const unsigned short* w2base = W2til + (size_t)c * 16 * 8192;

  const int arow = tid >> 1, ahalf = tid & 1;
  const long htok = (long)sTok[arow] * HIDDEN;

  f32x4 acc[4][4];
  #pragma unroll
  for (int i = 0; i < 4; ++i)
    #pragma unroll
    for (int j = 0; j < 4; ++j) { f32x4 z = {0.f, 0.f, 0.f, 0.f}; acc[i][j] = z; }

  for (int ks = 0; ks < 16; ++ks) {
    __syncthreads();
    const unsigned short* w1s = w1base + ks * 8192;
    #pragma unroll
    for (int j = 0; j < 4; ++j)
      gload16(w1s + j * 2048 + tid * 8, &sAB[8192 + j * 2048 + tid * 8]);
    {
      const float* hp = h + htok + ks * 64 + ahalf * 32;
      float4 v0 = *(const float4*)(hp + 0),  v1 = *(const float4*)(hp + 4);
      float4 v2 = *(const float4*)(hp + 8),  v3 = *(const float4*)(hp + 12);
      float4 v4 = *(const float4*)(hp + 16), v5 = *(const float4*)(hp + 20);
      float4 v6 = *(const float4*)(hp + 24), v7 = *(const float4*)(hp + 28);
      const int sb = arow * 64 + ahalf * 32;
      *(bf16x8*)&sAB[FSWZ(arow, sb + 0)]  = pack8(v0, v1);
      *(bf16x8*)&sAB[FSWZ(arow, sb + 8)]  = pack8(v2, v3);
      *(bf16x8*)&sAB[FSWZ(arow, sb + 16)] = pack8(v4, v5);
      *(bf16x8*)&sAB[FSWZ(arow, sb + 24)] = pack8(v6, v7);
    }
    __syncthreads();
    #pragma unroll
    for (int kk = 0; kk < 2; ++kk) {
      bf16x8 af[4], bfr[4];
      #pragma unroll
      for (int mf = 0; mf < 4; ++mf) {
        const int rw = wr * 64 + mf * 16 + lr;
        af[mf] = *(const bf16x8*)&sAB[FSWZ(rw, rw * 64 + kk * 32 + lg * 8)];
      }
      #pragma unroll
      for (int nf = 0; nf < 4; ++nf) {
        const int rn = wc * 64 + nf * 16 + lr;
        bfr[nf] = *(const bf16x8*)&sAB[8192 + FSWZ(rn, rn * 64 + kk * 32 + lg * 8)];
      }
      #pragma unroll
      for (int mf = 0; mf < 4; ++mf)
        #pragma unroll
        for (int nf = 0; nf < 4; ++nf)
          acc[mf][nf] = __builtin_amdgcn_mfma_f32_16x16x32_bf16(af[mf], bfr[nf], acc[mf][nf], 0, 0, 0);
    }
  }

  float b1v[4];
  #pragma unroll
  for (int nf = 0; nf < 4; ++nf) b1v[nf] = b1g[c * BOT + wc * 64 + nf * 16 + lr];
  #pragma unroll
  for (int mf = 0; mf < 4; ++mf)
    #pragma unroll
    for (int nf = 0; nf < 4; ++nf)
      #pragma unroll
      for (int r = 0; r < 4; ++r) {
        float x = acc[mf][nf][r] + b1v[nf];
        float g = 0.5f * x * (1.0f + erff(x * 0.70710678118654752f));
        const int m = wr * 64 + mf * 16 + lg * 4 + r;
        const int n = wc * 64 + nf * 16 + lr;
        sMid[FSWZ(m, m * 128 + n)] = f2bf(g);
      }

  for (int nc = 0; nc < 16; ++nc) {
    __syncthreads();
    #pragma unroll
    for (int j = 0; j < 4; ++j)
      gload16(w2base + nc * 8192 + j * 2048 + tid * 8, &sAB[j * 2048 + tid * 8]);
    __syncthreads();

    f32x4 a2[4][2];
    #pragma unroll
    for (int i = 0; i < 4; ++i)
      #pragma unroll
      for (int j = 0; j < 2; ++j) { f32x4 z = {0.f, 0.f, 0.f, 0.f}; a2[i][j] = z; }

    #pragma unroll
    for (int kk = 0; kk < 4; ++kk) {
      bf16x8 af[4], bfr[2];
      #pragma unroll
      for (int mf = 0; mf < 4; ++mf) {
        const int m = wr * 64 + mf * 16 + lr;
        af[mf] = *(const bf16x8*)&sMid[FSWZ(m, m * 128 + kk * 32 + lg * 8)];
      }
      #pragma unroll
      for (int nf = 0; nf < 2; ++nf) {
        const int rn = wc * 32 + nf * 16 + lr;
        bfr[nf] = *(const bf16x8*)&sAB[FSWZ(rn, rn * 128 + kk * 32 + lg * 8)];
      }
      #pragma unroll
      for (int mf = 0; mf < 4; ++mf)
        #pragma unroll
        for (int nf = 0; nf < 2; ++nf)
          a2[mf][nf] = __builtin_amdgcn_mfma_f32_16x16x32_bf16(af[mf], bfr[nf], a2[mf][nf], 0, 0, 0);
    }

    #pragma unroll
    for (int nf = 0; nf < 2; ++nf) {
      const int nn = nc * 64 + wc * 32 + nf * 16 + lr;
      const float b2v = b2g[c * HIDDEN + nn];
      #pragma unroll
      for (int mf = 0; mf < 4; ++mf)
        #pragma unroll
        for (int r = 0; r < 4; ++r) {
          const int m = wr * 64 + mf * 16 + lg * 4 + r;
          if (m < nvalid) {
            const long tk = (long)sTok[m] * HIDDEN;
            out[tk + nn] = h[tk + nn] + a2[mf][nf][r] + b2v;
          }
        }
    }
  }
}

// ---------------- launcher ----------------
extern "C" void kernel_launch(void* const* d_in, const int* in_sizes, int n_in,
                              void* d_out, int out_size, void* d_ws, size_t ws_size,
                              hipStream_t stream) {
  const float* h   = (const float*)d_in[0];
  const int*   ids = (const int*)d_in[1];
  const float* W1  = (const float*)d_in[2];
  const float* b1  = (const float*)d_in[3];
  const float* W2  = (const float*)d_in[4];
  const float* b2  = (const float*)d_in[5];
  float* out = (float*)d_out;

  char* ws = (char*)d_ws;
  int* counts  = (int*)ws;            // 16 ints
  int* cursor  = (int*)(ws + 64);     // 16 ints
  int* offsets = (int*)(ws + 128);    // 17 ints
  int* perm    = (int*)(ws + 256);    // 65536 ints, ends at 262400
  unsigned short* W1til = (unsigned short*)(ws + 262400);             // 4 MB
  unsigned short* W2buf = W1til + (size_t)16 * 16 * 8192;             // 4 MB (lin or til)
  unsigned short* midg  = W2buf + (size_t)16 * 16 * 8192;             // 16 MB
  const size_t need = 262400 + 2 * (size_t)16 * 16 * 8192 * 2 +
                      (size_t)NTOK * BOT * 2;

  k_zero<<<1, 64, 0, stream>>>(counts);
  k_hist<<<256, 256, 0, stream>>>(ids, counts);
  k_scan<<<1, 64, 0, stream>>>(counts, offsets, cursor);
  k_scatter<<<NTOK / 256, 256, 0, stream>>>(ids, cursor, perm);
  k_w1til<<<1024, 256, 0, stream>>>(W1, W1til);

  if (ws_size >= need) {
    k_w2lin<<<1024, 256, 0, stream>>>(W2, W2buf);
    const int nwg = NTOK / 64 + NUM_CLUSTERS;
    k_gemm1<<<nwg, 512, 0, stream>>>(h, b1, W1til, offsets, perm, midg);
    k_gemm2<<<nwg, 256, 0, stream>>>(h, b2, W2buf, offsets, perm, midg, out);
  } else {
    k_w2til<<<1024, 256, 0, stream>>>(W2, W2buf);
    k_fused<<<NTOK / 128 + NUM_CLUSTERS, 256, 0, stream>>>(
        h, b1, b2, W1til, W2buf, offsets, perm, out);
  }
}

// Round 11
// 268.519 us; speedup vs baseline: 1.2305x; 1.2305x over previous
//
#include <hip/hip_runtime.h>
#include <hip/hip_bf16.h>
#include <math.h>

#define NUM_CLUSTERS 16
#define HIDDEN 1024
#define BOT 128
#define NTOK 65536

typedef __attribute__((ext_vector_type(8))) short bf16x8;
typedef __attribute__((ext_vector_type(4))) float f32x4;

typedef __attribute__((address_space(3))) unsigned int lds_u32;
typedef const __attribute__((address_space(1))) unsigned int glb_u32;

__device__ __forceinline__ void gload16(const void* g, void* l) {
  __builtin_amdgcn_global_load_lds((glb_u32*)g, (lds_u32*)l, 16, 0, 0);
}

__device__ __forceinline__ unsigned short f2bf(float x) {
  union { float f; unsigned u; } v; v.f = x;
  unsigned r = v.u + 0x7fffu + ((v.u >> 16) & 1u);
  return (unsigned short)(r >> 16);
}

__device__ __forceinline__ bf16x8 pack8(float4 a, float4 b) {
  bf16x8 r;
  r[0] = (short)f2bf(a.x); r[1] = (short)f2bf(a.y);
  r[2] = (short)f2bf(a.z); r[3] = (short)f2bf(a.w);
  r[4] = (short)f2bf(b.x); r[5] = (short)f2bf(b.y);
  r[6] = (short)f2bf(b.z); r[7] = (short)f2bf(b.w);
  return r;
}

// short-index swizzle: XOR short-idx bits 3..5 with (row&7) -> 16B-chunk spread
#define SWZS(row, sidx) ((sidx) ^ (((row) & 7) << 3))
// f32-index swizzle (16B granule)
#define SW4(row, fidx) ((fidx) ^ (((row) & 7) << 2))

#define SCB() __builtin_amdgcn_sched_barrier(0)
#define VMW(n)                                          \
  do {                                                  \
    SCB();                                              \
    asm volatile("s_waitcnt vmcnt(" #n ")" ::: "memory"); \
    SCB();                                              \
  } while (0)
#define SBAR()                                  \
  do {                                          \
    SCB();                                      \
    __builtin_amdgcn_s_barrier();               \
    SCB();                                      \
  } while (0)
#define LGKM0() asm volatile("s_waitcnt lgkmcnt(0)" ::: "memory")

// bijective XCD-chunk swizzle (m204)
__device__ __forceinline__ int xcd_swz(int bid, int nwg) {
  const int nx = 8;
  int q = nwg / nx, r = nwg % nx;
  int xcd = bid % nx, idx = bid / nx;
  int b = (xcd < r) ? xcd * (q + 1) : r * (q + 1) + (xcd - r) * q;
  return b + idx;
}

// ---------------- prep kernels ----------------

__global__ void k_zero(int* p) {
  if (threadIdx.x < 64) p[threadIdx.x] = 0;
}

__global__ void k_hist(const int* __restrict__ ids, int* __restrict__ counts) {
  __shared__ int lh[NUM_CLUSTERS];
  if (threadIdx.x < NUM_CLUSTERS) lh[threadIdx.x] = 0;
  __syncthreads();
  int i = blockIdx.x * blockDim.x + threadIdx.x;
  int stride = gridDim.x * blockDim.x;
  for (; i < NTOK; i += stride) atomicAdd(&lh[ids[i]], 1);
  __syncthreads();
  if (threadIdx.x < NUM_CLUSTERS) atomicAdd(&counts[threadIdx.x], lh[threadIdx.x]);
}

__global__ void k_scan(const int* __restrict__ counts, int* __restrict__ offsets,
                       int* __restrict__ cursor) {
  if (threadIdx.x == 0 && blockIdx.x == 0) {
    int s = 0;
    for (int c = 0; c < NUM_CLUSTERS; ++c) {
      offsets[c] = s; cursor[c] = s; s += counts[c];
    }
    offsets[NUM_CLUSTERS] = s;
  }
}

__global__ void k_scatter(const int* __restrict__ ids, int* cursor,
                          int* __restrict__ perm) {
  __shared__ int lh[NUM_CLUSTERS], lbase[NUM_CLUSTERS];
  const int tid = threadIdx.x;
  if (tid < NUM_CLUSTERS) lh[tid] = 0;
  __syncthreads();
  const int i = blockIdx.x * 256 + tid;
  const int cc = ids[i];
  const int r = atomicAdd(&lh[cc], 1);
  __syncthreads();
  if (tid < NUM_CLUSTERS) lbase[tid] = atomicAdd(&cursor[tid], lh[tid]);
  __syncthreads();
  perm[lbase[cc] + r] = i;
}

// W1 [16][1024][128] -> per-(c,ks) 16KB swizzled images of W1^T [n=128][k=64]
__global__ void k_w1til(const float* __restrict__ W1, unsigned short* __restrict__ outw) {
  const int id = blockIdx.x * 256 + threadIdx.x;   // 262144 total
  const int c  = id >> 14;
  const int ks = (id >> 10) & 15;
  const int q  = id & 1023;
  const int o  = q << 4;                 // stored byte offset in image
  const int row = o >> 7;                // n
  const int lb  = (o & 127) ^ ((row & 7) << 4);
  const int k0  = ks * 64 + (lb >> 1);   // 8 consecutive k
  const float* src = W1 + ((size_t)c * HIDDEN + k0) * BOT + row;
  unsigned short v[8];
  #pragma unroll
  for (int j = 0; j < 8; ++j) v[j] = f2bf(src[(size_t)j * BOT]);
  *(uint4*)((char*)outw + ((size_t)(c * 16 + ks)) * 16384 + o) = *(const uint4*)v;
}

// W2 [16][128][1024] -> fragment-linear layout:
// outw[((c*16 + nc)*16 + kk*4 + nf)*512 + l*8 + i] =
//   bf16(W2[c][kk*32 + (l>>4)*8 + i][nc*64 + nf*16 + (l&15)])
__global__ void k_w2lin(const float* __restrict__ W2, unsigned short* __restrict__ outw) {
  const int id = blockIdx.x * 256 + threadIdx.x;   // 262144 total
  const int c   = id >> 14;
  const int rem = id & 16383;
  const int fg  = rem >> 6;            // nc*16 + kk*4 + nf
  const int l   = rem & 63;
  const int nc  = fg >> 4, kk = (fg >> 2) & 3, nf = fg & 3;
  const int n   = nc * 64 + nf * 16 + (l & 15);
  const int k0  = kk * 32 + (l >> 4) * 8;
  const float* src = W2 + ((size_t)c * BOT + k0) * HIDDEN + n;
  unsigned short v[8];
  #pragma unroll
  for (int j = 0; j < 8; ++j) v[j] = f2bf(src[(size_t)j * HIDDEN]);
  *(uint4*)(outw + (size_t)id * 8) = *(const uint4*)v;
}

// W2 [16][128][1024] -> per-(c,nc) 16KB swizzled images (FALLBACK path only)
__global__ void k_w2til(const float* __restrict__ W2, unsigned short* __restrict__ outw) {
  const int id = blockIdx.x * 256 + threadIdx.x;   // 262144 total
  const int c  = id >> 14;
  const int nc = (id >> 10) & 15;
  const int q  = id & 1023;
  const int o  = q << 4;
  const int row = o >> 8;                // n' 0..63
  const int lb  = (o & 255) ^ ((row & 7) << 4);
  const int b0  = lb >> 1;               // 8 consecutive b
  const int n   = nc * 64 + row;
  const float* src = W2 + ((size_t)c * BOT + b0) * HIDDEN + n;
  unsigned short v[8];
  #pragma unroll
  for (int j = 0; j < 8; ++j) v[j] = f2bf(src[(size_t)j * HIDDEN]);
  *(uint4*)((char*)outw + ((size_t)(c * 16 + nc)) * 16384 + o) = *(const uint4*)v;
}

// ---- common tile locator: TM tokens per tile ----
__device__ __forceinline__ bool locate(const int* offsets, int bid, int TMv,
                                       int& c, int& base, int& nvalid) {
  int t = bid;
  for (c = 0; c < NUM_CLUSTERS; ++c) {
    int cnt = offsets[c + 1] - offsets[c];
    int nt = (cnt + TMv - 1) / TMv;
    if (t < nt) {
      base = offsets[c] + t * TMv;
      nvalid = min(TMv, offsets[c + 1] - base);
      return true;
    }
    t -= nt;
  }
  return false;
}

// ---------------- pass 1: mid = gelu(h@W1 + b1) (unchanged from R9) ----------------
__global__ __launch_bounds__(512, 6) void k_gemm1(
    const float* __restrict__ h, const float* __restrict__ b1g,
    const unsigned short* __restrict__ W1til, const int* __restrict__ offsets,
    const int* __restrict__ perm, unsigned short* __restrict__ midg) {

  __shared__ __align__(16) unsigned short sA[2][4096];
  __shared__ __align__(16) unsigned short sB[2][8192];
  __shared__ int sTok[64];

  const int tid = threadIdx.x;
  const int l = tid & 63, w = tid >> 6;
  const int lr = l & 15, lg = l >> 4;
  const int wr = w >> 2, wc = w & 3;
  const int row = tid >> 3, o8 = tid & 7;

  const int nwg = NTOK / 64 + NUM_CLUSTERS;
  int c, base, nvalid;
  if (!locate(offsets, xcd_swz(blockIdx.x, nwg), 64, c, base, nvalid)) return;

  if (tid < 64) sTok[tid] = perm[base + min(tid, nvalid - 1)];
  LGKM0();
  SBAR();

  const unsigned short* w1base = W1til + (size_t)c * 16 * 8192;
  const float* hrow = h + (long)sTok[row] * HIDDEN + o8 * 8;

  float4 vaA[2], vaB[2];
  vaA[0] = *(const float4*)(hrow);       vaA[1] = *(const float4*)(hrow + 4);
  SCB();
  gload16(w1base + tid * 8, &sB[0][tid * 8]);
  gload16(w1base + 4096 + tid * 8, &sB[0][4096 + tid * 8]);
  SCB();
  vaB[0] = *(const float4*)(hrow + 64);  vaB[1] = *(const float4*)(hrow + 68);
  SCB();
  *(bf16x8*)&sA[0][SWZS(row, row * 64 + o8 * 8)] = pack8(vaA[0], vaA[1]);
  LGKM0();
  VMW(2);
  SBAR();

  f32x4 acc[2][2];
  #pragma unroll
  for (int i = 0; i < 2; ++i)
    #pragma unroll
    for (int j = 0; j < 2; ++j) { f32x4 z = {0.f, 0.f, 0.f, 0.f}; acc[i][j] = z; }

#define G1_MFMA(CUR)                                                          \
  do {                                                                        \
    _Pragma("unroll")                                                         \
    for (int kk = 0; kk < 2; ++kk) {                                          \
      bf16x8 af[2], bfr[2];                                                   \
      _Pragma("unroll")                                                       \
      for (int mf = 0; mf < 2; ++mf) {                                        \
        const int m = wr * 32 + mf * 16 + lr;                                 \
        af[mf] = *(const bf16x8*)&sA[CUR][SWZS(m, m * 64 + kk * 32 + lg * 8)];\
      }                                                                       \
      _Pragma("unroll")                                                       \
      for (int nf = 0; nf < 2; ++nf) {                                        \
        const int rn = wc * 32 + nf * 16 + lr;                                \
        bfr[nf] = *(const bf16x8*)&sB[CUR][SWZS(rn, rn * 64 + kk * 32 + lg * 8)]; \
      }                                                                       \
      _Pragma("unroll")                                                       \
      for (int mf = 0; mf < 2; ++mf)                                          \
        _Pragma("unroll")                                                     \
        for (int nf = 0; nf < 2; ++nf)                                        \
          acc[mf][nf] = __builtin_amdgcn_mfma_f32_16x16x32_bf16(              \
              af[mf], bfr[nf], acc[mf][nf], 0, 0, 0);                         \
    }                                                                         \
  } while (0)

  #pragma unroll
  for (int t = 0; t < 16; ++t) {
    const int cur = t & 1;
    if (t < 15) {
      const unsigned short* w1s = w1base + (t + 1) * 8192;
      gload16(w1s + tid * 8, &sB[cur ^ 1][tid * 8]);
      gload16(w1s + 4096 + tid * 8, &sB[cur ^ 1][4096 + tid * 8]);
      SCB();
    }
    if (t < 14) {
      if (t & 1) {
        vaB[0] = *(const float4*)(hrow + (t + 2) * 64);
        vaB[1] = *(const float4*)(hrow + (t + 2) * 64 + 4);
      } else {
        vaA[0] = *(const float4*)(hrow + (t + 2) * 64);
        vaA[1] = *(const float4*)(hrow + (t + 2) * 64 + 4);
      }
      SCB();
    }
    G1_MFMA(cur);
    if (t < 15) {
      const float4* src = ((t + 1) & 1) ? vaB : vaA;
      *(bf16x8*)&sA[cur ^ 1][SWZS(row, row * 64 + o8 * 8)] = pack8(src[0], src[1]);
      if (t < 14) { VMW(2); } else { VMW(0); }
      LGKM0();
      SBAR();
    }
  }
#undef G1_MFMA

  float b1v[2];
  #pragma unroll
  for (int nf = 0; nf < 2; ++nf) b1v[nf] = b1g[c * BOT + wc * 32 + nf * 16 + lr];
  #pragma unroll
  for (int mf = 0; mf < 2; ++mf) {
    #pragma unroll
    for (int nf = 0; nf < 2; ++nf) {
      #pragma unroll
      for (int r = 0; r < 4; ++r) {
        float x = acc[mf][nf][r] + b1v[nf];
        float g = 0.5f * x * (1.0f + erff(x * 0.70710678118654752f));
        const int m = wr * 32 + mf * 16 + lg * 4 + r;
        if (m < nvalid) {
          const int n = wc * 32 + nf * 16 + lr;
          midg[(size_t)(base + m) * BOT + n] = f2bf(g);
        }
      }
    }
  }
}

// ---------------- pass 2: out = h + mid@W2 + b2 — 1 barrier/chunk ----------------
// 512 threads = 8 waves: 4 row-blocks (16 tokens) x 2 col-halves (32 cols/chunk).
// A (mid) in registers; B via gload_lds double-buffer of fragment-linear W2lin
// (lane-linear both sides); epilogue via wave-private f32 LDS tile (no barrier).
// Per chunk: hv/bv -> B(nc+1) gloads -> MFMA(8) -> roundtrip -> stores ->
// vmcnt(2) [drains B(nc+1), leaves 2 stores] -> s_barrier.
// Stores are UNCONDITIONAL: clamped rows duplicate row nvalid-1's exact value,
// keeping vmcnt wave-uniform.

__global__ __launch_bounds__(512, 6) void k_gemm2(
    const float* __restrict__ h, const float* __restrict__ b2g,
    const unsigned short* __restrict__ W2lin, const int* __restrict__ offsets,
    const int* __restrict__ perm, const unsigned short* __restrict__ midg,
    float* __restrict__ out) {

  __shared__ __align__(16) unsigned short sB[2][8192];   // dbuf 16KB chunk images
  __shared__ __align__(16) float sOut[8 * 512];          // 8 waves x 16x32 f32
  __shared__ int sTok[64];

  const int tid = threadIdx.x;
  const int l = tid & 63, w = tid >> 6;
  const int lr = l & 15, lg = l >> 4;
  const int wrow = (w & 3) * 16;       // wave's 16-token row block
  const int ch = w >> 2;               // col half of the 64-col chunk

  const int nwg = NTOK / 64 + NUM_CLUSTERS;
  int c, base, nvalid;
  if (!locate(offsets, xcd_swz(blockIdx.x, nwg), 64, c, base, nvalid)) return;

  if (tid < 64) sTok[tid] = perm[base + min(tid, nvalid - 1)];
  __syncthreads();

  const unsigned short* wlin = W2lin + (size_t)c * 131072;

  // A fragments: wave's 16 mid rows (clamped), K=128 -> 4 bf16x8
  const long amrow = (long)(base + min(wrow + lr, nvalid - 1)) * BOT;
  bf16x8 ma[4];
  #pragma unroll
  for (int kk = 0; kk < 4; ++kk)
    ma[kk] = *(const bf16x8*)(midg + amrow + kk * 32 + lg * 8);

  // epilogue roles: lane -> (row er in wave block, 8-col quarter of 32)
  const int er = l >> 2, ecq = l & 3;
  const long etok = (long)sTok[wrow + er] * HIDDEN;
  const float* hrow = h + etok;
  float* orow = out + etok;
  float* sW = sOut + w * 512;
  const float* b2c = b2g + c * HIDDEN;
  const int ecol = ch * 32 + ecq * 8;  // col offset within the 64-col chunk

  // prologue: B(0) staged, drained
  gload16(wlin + tid * 8, &sB[0][tid * 8]);
  gload16(wlin + 4096 + tid * 8, &sB[0][4096 + tid * 8]);
  VMW(0);
  SBAR();

  for (int nc = 0; nc < 16; ++nc) {
    const int cur = nc & 1;
    // this chunk's residual/bias (issued BEFORE B(nc+1) so their auto-wait
    // never drains the prefetch)
    float4 hv0 = *(const float4*)(hrow + nc * 64 + ecol);
    float4 hv1 = *(const float4*)(hrow + nc * 64 + ecol + 4);
    float4 bv0 = *(const float4*)(b2c + nc * 64 + ecol);
    float4 bv1 = *(const float4*)(b2c + nc * 64 + ecol + 4);
    SCB();
    if (nc < 15) {
      const unsigned short* ws2 = wlin + (nc + 1) * 8192;
      gload16(ws2 + tid * 8, &sB[cur ^ 1][tid * 8]);
      gload16(ws2 + 4096 + tid * 8, &sB[cur ^ 1][4096 + tid * 8]);
      SCB();
    }

    f32x4 acc[2];
    { f32x4 z = {0.f, 0.f, 0.f, 0.f}; acc[0] = z; acc[1] = z; }
    #pragma unroll
    for (int kk = 0; kk < 4; ++kk) {
      #pragma unroll
      for (int nf = 0; nf < 2; ++nf) {
        const bf16x8 bf =
            *(const bf16x8*)&sB[cur][(kk * 4 + ch * 2 + nf) * 512 + l * 8];
        acc[nf] = __builtin_amdgcn_mfma_f32_16x16x32_bf16(ma[kk], bf, acc[nf], 0, 0, 0);
      }
    }

    // wave-private f32 roundtrip (16x32 tile, row-swizzled, no barrier)
    #pragma unroll
    for (int nf = 0; nf < 2; ++nf) {
      #pragma unroll
      for (int r = 0; r < 4; ++r) {
        const int m = lg * 4 + r;
        const int n = nf * 16 + lr;
        sW[(m * 32 + n) ^ ((m & 7) << 2)] = acc[nf][r];
      }
    }
    {
      const int fb = er * 32 + ecq * 8;
      const float4 y0 = *(const float4*)&sW[(fb) ^ ((er & 7) << 2)];
      const float4 y1 = *(const float4*)&sW[(fb + 4) ^ ((er & 7) << 2)];
      float4 o0, o1;
      o0.x = y0.x + hv0.x + bv0.x; o0.y = y0.y + hv0.y + bv0.y;
      o0.z = y0.z + hv0.z + bv0.z; o0.w = y0.w + hv0.w + bv0.w;
      o1.x = y1.x + hv1.x + bv1.x; o1.y = y1.y + hv1.y + bv1.y;
      o1.z = y1.z + hv1.z + bv1.z; o1.w = y1.w + hv1.w + bv1.w;
      *(float4*)(orow + nc * 64 + ecol)     = o0;
      *(float4*)(orow + nc * 64 + ecol + 4) = o1;
    }
    if (nc < 15) {
      VMW(2);   // drain B(nc+1); the 2 stores stay in flight
      SBAR();   // everyone done with sB[cur] -> next chunk may overwrite it
    }
  }
}

// ---------------- fallback fused kernel (ws too small): TM=128 ----------------
#define FSWZ(row, sidx) ((sidx) ^ (((row) & 7) << 3))

__global__ __launch_bounds__(256, 2) void k_fused(
    const float* __restrict__ h, const float* __restrict__ b1g,
    const float* __restrict__ b2g, const unsigned short* __restrict__ W1til,
    const unsigned short* __restrict__ W2til, const int* __restrict__ offsets,
    const int* __restrict__ perm, float* __restrict__ out) {

  __shared__ __align__(16) unsigned short sAB[16384];
  __shared__ __align__(16) unsigned short sMid[16384];
  __shared__ int sTok[128];

  const int tid = threadIdx.x;
  const int l = tid & 63, w = tid >> 6;
  const int wr = w >> 1, wc = w & 1;
  const int lr = l & 15, lg = l >> 4;

  int c, base, nvalid;
  if (!locate(offsets, blockIdx.x, 128, c, base, nvalid)) return;

  if (tid < 128) sTok[tid] = perm[base + min(tid, nvalid - 1)];
  __syncthreads();

  const unsigned short* w1base = W1til + (size_t)c * 16 * 8192;
  const unsigned short* w2base = W2til + (size_t)c * 16 * 8192;

  const int arow = tid >> 1, ahalf = tid & 1;
  const long htok = (long)sTok[arow] * HIDDEN;

  f32x4 acc[4][4];
  #pragma unroll
  for (int i = 0; i < 4; ++i)
    #pragma unroll
    for (int j = 0; j < 4; ++j) { f32x4 z = {0.f, 0.f, 0.f, 0.f}; acc[i][j] = z; }

  for (int ks = 0; ks < 16; ++ks) {
    __syncthreads();
    const unsigned short* w1s = w1base + ks * 8192;
    #pragma unroll
    for (int j = 0; j < 4; ++j)
      gload16(w1s + j * 2048 + tid * 8, &sAB[8192 + j * 2048 + tid * 8]);
    {
      const float* hp = h + htok + ks * 64 + ahalf * 32;
      float4 v0 = *(const float4*)(hp + 0),  v1 = *(const float4*)(hp + 4);
      float4 v2 = *(const float4*)(hp + 8),  v3 = *(const float4*)(hp + 12);
      float4 v4 = *(const float4*)(hp + 16), v5 = *(const float4*)(hp + 20);
      float4 v6 = *(const float4*)(hp + 24), v7 = *(const float4*)(hp + 28);
      const int sb = arow * 64 + ahalf * 32;
      *(bf16x8*)&sAB[FSWZ(arow, sb + 0)]  = pack8(v0, v1);
      *(bf16x8*)&sAB[FSWZ(arow, sb + 8)]  = pack8(v2, v3);
      *(bf16x8*)&sAB[FSWZ(arow, sb + 16)] = pack8(v4, v5);
      *(bf16x8*)&sAB[FSWZ(arow, sb + 24)] = pack8(v6, v7);
    }
    __syncthreads();
    #pragma unroll
    for (int kk = 0; kk < 2; ++kk) {
      bf16x8 af[4], bfr[4];
      #pragma unroll
      for (int mf = 0; mf < 4; ++mf) {
        const int rw = wr * 64 + mf * 16 + lr;
        af[mf] = *(const bf16x8*)&sAB[FSWZ(rw, rw * 64 + kk * 32 + lg * 8)];
      }
      #pragma unroll
      for (int nf = 0; nf < 4; ++nf) {
        const int rn = wc * 64 + nf * 16 + lr;
        bfr[nf] = *(const bf16x8*)&sAB[8192 + FSWZ(rn, rn * 64 + kk * 32 + lg * 8)];
      }
      #pragma unroll
      for (int mf = 0; mf < 4; ++mf)
        #pragma unroll
        for (int nf = 0; nf < 4; ++nf)
          acc[mf][nf] = __builtin_amdgcn_mfma_f32_16x16x32_bf16(af[mf], bfr[nf], acc[mf][nf], 0, 0, 0);
    }
  }

  float b1v[4];
  #pragma unroll
  for (int nf = 0; nf < 4; ++nf) b1v[nf] = b1g[c * BOT + wc * 64 + nf * 16 + lr];
  #pragma unroll
  for (int mf = 0; mf < 4; ++mf)
    #pragma unroll
    for (int nf = 0; nf < 4; ++nf)
      #pragma unroll
      for (int r = 0; r < 4; ++r) {
        float x = acc[mf][nf][r] + b1v[nf];
        float g = 0.5f * x * (1.0f + erff(x * 0.70710678118654752f));
        const int m = wr * 64 + mf * 16 + lg * 4 + r;
        const int n = wc * 64 + nf * 16 + lr;
        sMid[FSWZ(m, m * 128 + n)] = f2bf(g);
      }

  for (int nc = 0; nc < 16; ++nc) {
    __syncthreads();
    #pragma unroll
    for (int j = 0; j < 4; ++j)
      gload16(w2base + nc * 8192 + j * 2048 + tid * 8, &sAB[j * 2048 + tid * 8]);
    __syncthreads();

    f32x4 a2[4][2];
    #pragma unroll
    for (int i = 0; i < 4; ++i)
      #pragma unroll
      for (int j = 0; j < 2; ++j) { f32x4 z = {0.f, 0.f, 0.f, 0.f}; a2[i][j] = z; }

    #pragma unroll
    for (int kk = 0; kk < 4; ++kk) {
      bf16x8 af[4], bfr[2];
      #pragma unroll
      for (int mf = 0; mf < 4; ++mf) {
        const int m = wr * 64 + mf * 16 + lr;
        af[mf] = *(const bf16x8*)&sMid[FSWZ(m, m * 128 + kk * 32 + lg * 8)];
      }
      #pragma unroll
      for (int nf = 0; nf < 2; ++nf) {
        const int rn = wc * 32 + nf * 16 + lr;
        bfr[nf] = *(const bf16x8*)&sAB[FSWZ(rn, rn * 128 + kk * 32 + lg * 8)];
      }
      #pragma unroll
      for (int mf = 0; mf < 4; ++mf)
        #pragma unroll
        for (int nf = 0; nf < 2; ++nf)
          a2[mf][nf] = __builtin_amdgcn_mfma_f32_16x16x32_bf16(af[mf], bfr[nf], a2[mf][nf], 0, 0, 0);
    }

    #pragma unroll
    for (int nf = 0; nf < 2; ++nf) {
      const int nn = nc * 64 + wc * 32 + nf * 16 + lr;
      const float b2v = b2g[c * HIDDEN + nn];
      #pragma unroll
      for (int mf = 0; mf < 4; ++mf)
        #pragma unroll
        for (int r = 0; r < 4; ++r) {
          const int m = wr * 64 + mf * 16 + lg * 4 + r;
          if (m < nvalid) {
            const long tk = (long)sTok[m] * HIDDEN;
            out[tk + nn] = h[tk + nn] + a2[mf][nf][r] + b2v;
          }
        }
    }
  }
}

// ---------------- launcher ----------------
extern "C" void kernel_launch(void* const* d_in, const int* in_sizes, int n_in,
                              void* d_out, int out_size, void* d_ws, size_t ws_size,
                              hipStream_t stream) {
  const float* h   = (const float*)d_in[0];
  const int*   ids = (const int*)d_in[1];
  const float* W1  = (const float*)d_in[2];
  const float* b1  = (const float*)d_in[3];
  const float* W2  = (const float*)d_in[4];
  const float* b2  = (const float*)d_in[5];
  float* out = (float*)d_out;

  char* ws = (char*)d_ws;
  int* counts  = (int*)ws;            // 16 ints
  int* cursor  = (int*)(ws + 64);     // 16 ints
  int* offsets = (int*)(ws + 128);    // 17 ints
  int* perm    = (int*)(ws + 256);    // 65536 ints, ends at 262400
  unsigned short* W1til = (unsigned short*)(ws + 262400);             // 4 MB
  unsigned short* W2buf = W1til + (size_t)16 * 16 * 8192;             // 4 MB (lin or til)
  unsigned short* midg  = W2buf + (size_t)16 * 16 * 8192;             // 16 MB
  const size_t need = 262400 + 2 * (size_t)16 * 16 * 8192 * 2 +
                      (size_t)NTOK * BOT * 2;

  k_zero<<<1, 64, 0, stream>>>(counts);
  k_hist<<<256, 256, 0, stream>>>(ids, counts);
  k_scan<<<1, 64, 0, stream>>>(counts, offsets, cursor);
  k_scatter<<<NTOK / 256, 256, 0, stream>>>(ids, cursor, perm);
  k_w1til<<<1024, 256, 0, stream>>>(W1, W1til);

  if (ws_size >= need) {
    k_w2lin<<<1024, 256, 0, stream>>>(W2, W2buf);
    const int nwg = NTOK / 64 + NUM_CLUSTERS;
    k_gemm1<<<nwg, 512, 0, stream>>>(h, b1, W1til, offsets, perm, midg);
    k_gemm2<<<nwg, 512, 0, stream>>>(h, b2, W2buf, offsets, perm, midg, out);
  } else {
    k_w2til<<<1024, 256, 0, stream>>>(W2, W2buf);
    k_fused<<<NTOK / 128 + NUM_CLUSTERS, 256, 0, stream>>>(
        h, b1, b2, W1til, W2buf, offsets, perm, out);
  }
}

// Round 12
// 244.322 us; speedup vs baseline: 1.3524x; 1.0990x over previous
//
#include <hip/hip_runtime.h>
#include <hip/hip_bf16.h>
#include <math.h>

#define NUM_CLUSTERS 16
#define HIDDEN 1024
#define BOT 128
#define NTOK 65536

typedef __attribute__((ext_vector_type(8))) short bf16x8;
typedef __attribute__((ext_vector_type(4))) float f32x4;

typedef __attribute__((address_space(3))) unsigned int lds_u32;
typedef const __attribute__((address_space(1))) unsigned int glb_u32;

__device__ __forceinline__ void gload16(const void* g, void* l) {
  __builtin_amdgcn_global_load_lds((glb_u32*)g, (lds_u32*)l, 16, 0, 0);
}

__device__ __forceinline__ unsigned short f2bf(float x) {
  union { float f; unsigned u; } v; v.f = x;
  unsigned r = v.u + 0x7fffu + ((v.u >> 16) & 1u);
  return (unsigned short)(r >> 16);
}

__device__ __forceinline__ bf16x8 pack8(float4 a, float4 b) {
  bf16x8 r;
  r[0] = (short)f2bf(a.x); r[1] = (short)f2bf(a.y);
  r[2] = (short)f2bf(a.z); r[3] = (short)f2bf(a.w);
  r[4] = (short)f2bf(b.x); r[5] = (short)f2bf(b.y);
  r[6] = (short)f2bf(b.z); r[7] = (short)f2bf(b.w);
  return r;
}

// short-index swizzle: XOR short-idx bits 3..5 with (row&7) -> 16B-chunk spread
#define SWZS(row, sidx) ((sidx) ^ (((row) & 7) << 3))

#define SCB() __builtin_amdgcn_sched_barrier(0)
#define VMW(n)                                          \
  do {                                                  \
    SCB();                                              \
    asm volatile("s_waitcnt vmcnt(" #n ")" ::: "memory"); \
    SCB();                                              \
  } while (0)
#define SBAR()                                  \
  do {                                          \
    SCB();                                      \
    __builtin_amdgcn_s_barrier();               \
    SCB();                                      \
  } while (0)
#define LGKM0() asm volatile("s_waitcnt lgkmcnt(0)" ::: "memory")

// bijective XCD-chunk swizzle (m204)
__device__ __forceinline__ int xcd_swz(int bid, int nwg) {
  const int nx = 8;
  int q = nwg / nx, r = nwg % nx;
  int xcd = bid % nx, idx = bid / nx;
  int b = (xcd < r) ? xcd * (q + 1) : r * (q + 1) + (xcd - r) * q;
  return b + idx;
}

// ---------------- prep kernels ----------------

__global__ void k_zero(int* p) {
  if (threadIdx.x < 64) p[threadIdx.x] = 0;
}

__global__ void k_hist(const int* __restrict__ ids, int* __restrict__ counts) {
  __shared__ int lh[NUM_CLUSTERS];
  if (threadIdx.x < NUM_CLUSTERS) lh[threadIdx.x] = 0;
  __syncthreads();
  int i = blockIdx.x * blockDim.x + threadIdx.x;
  int stride = gridDim.x * blockDim.x;
  for (; i < NTOK; i += stride) atomicAdd(&lh[ids[i]], 1);
  __syncthreads();
  if (threadIdx.x < NUM_CLUSTERS) atomicAdd(&counts[threadIdx.x], lh[threadIdx.x]);
}

__global__ void k_scan(const int* __restrict__ counts, int* __restrict__ offsets,
                       int* __restrict__ cursor) {
  if (threadIdx.x == 0 && blockIdx.x == 0) {
    int s = 0;
    for (int c = 0; c < NUM_CLUSTERS; ++c) {
      offsets[c] = s; cursor[c] = s; s += counts[c];
    }
    offsets[NUM_CLUSTERS] = s;
  }
}

__global__ void k_scatter(const int* __restrict__ ids, int* cursor,
                          int* __restrict__ perm) {
  __shared__ int lh[NUM_CLUSTERS], lbase[NUM_CLUSTERS];
  const int tid = threadIdx.x;
  if (tid < NUM_CLUSTERS) lh[tid] = 0;
  __syncthreads();
  const int i = blockIdx.x * 256 + tid;
  const int cc = ids[i];
  const int r = atomicAdd(&lh[cc], 1);
  __syncthreads();
  if (tid < NUM_CLUSTERS) lbase[tid] = atomicAdd(&cursor[tid], lh[tid]);
  __syncthreads();
  perm[lbase[cc] + r] = i;
}

// W1 [16][1024][128] -> per-(c,ks) 16KB swizzled images of W1^T [n=128][k=64]
__global__ void k_w1til(const float* __restrict__ W1, unsigned short* __restrict__ outw) {
  const int id = blockIdx.x * 256 + threadIdx.x;   // 262144 total
  const int c  = id >> 14;
  const int ks = (id >> 10) & 15;
  const int q  = id & 1023;
  const int o  = q << 4;                 // stored byte offset in image
  const int row = o >> 7;                // n
  const int lb  = (o & 127) ^ ((row & 7) << 4);
  const int k0  = ks * 64 + (lb >> 1);   // 8 consecutive k
  const float* src = W1 + ((size_t)c * HIDDEN + k0) * BOT + row;
  unsigned short v[8];
  #pragma unroll
  for (int j = 0; j < 8; ++j) v[j] = f2bf(src[(size_t)j * BOT]);
  *(uint4*)((char*)outw + ((size_t)(c * 16 + ks)) * 16384 + o) = *(const uint4*)v;
}

// W2 [16][128][1024] -> fragment-linear layout:
// outw[((c*16 + nc)*16 + kk*4 + nf)*512 + l*8 + i] =
//   bf16(W2[c][kk*32 + (l>>4)*8 + i][nc*64 + nf*16 + (l&15)])
__global__ void k_w2lin(const float* __restrict__ W2, unsigned short* __restrict__ outw) {
  const int id = blockIdx.x * 256 + threadIdx.x;   // 262144 total
  const int c   = id >> 14;
  const int rem = id & 16383;
  const int fg  = rem >> 6;            // nc*16 + kk*4 + nf
  const int l   = rem & 63;
  const int nc  = fg >> 4, kk = (fg >> 2) & 3, nf = fg & 3;
  const int n   = nc * 64 + nf * 16 + (l & 15);
  const int k0  = kk * 32 + (l >> 4) * 8;
  const float* src = W2 + ((size_t)c * BOT + k0) * HIDDEN + n;
  unsigned short v[8];
  #pragma unroll
  for (int j = 0; j < 8; ++j) v[j] = f2bf(src[(size_t)j * HIDDEN]);
  *(uint4*)(outw + (size_t)id * 8) = *(const uint4*)v;
}

// W2 [16][128][1024] -> per-(c,nc) 16KB swizzled images (FALLBACK path only)
__global__ void k_w2til(const float* __restrict__ W2, unsigned short* __restrict__ outw) {
  const int id = blockIdx.x * 256 + threadIdx.x;   // 262144 total
  const int c  = id >> 14;
  const int nc = (id >> 10) & 15;
  const int q  = id & 1023;
  const int o  = q << 4;
  const int row = o >> 8;                // n' 0..63
  const int lb  = (o & 255) ^ ((row & 7) << 4);
  const int b0  = lb >> 1;               // 8 consecutive b
  const int n   = nc * 64 + row;
  const float* src = W2 + ((size_t)c * BOT + b0) * HIDDEN + n;
  unsigned short v[8];
  #pragma unroll
  for (int j = 0; j < 8; ++j) v[j] = f2bf(src[(size_t)j * HIDDEN]);
  *(uint4*)((char*)outw + ((size_t)(c * 16 + nc)) * 16384 + o) = *(const uint4*)v;
}

// ---- common tile locator: TM tokens per tile ----
__device__ __forceinline__ bool locate(const int* offsets, int bid, int TMv,
                                       int& c, int& base, int& nvalid) {
  int t = bid;
  for (c = 0; c < NUM_CLUSTERS; ++c) {
    int cnt = offsets[c + 1] - offsets[c];
    int nt = (cnt + TMv - 1) / TMv;
    if (t < nt) {
      base = offsets[c] + t * TMv;
      nvalid = min(TMv, offsets[c + 1] - base);
      return true;
    }
    t -= nt;
  }
  return false;
}

// ---------------- FUSED: out = h + gelu(h@W1+b1)@W2 + b2 per 64-token tile ----
// 512 threads (8 waves). Phase 1 = R9 gemm1 (counted vmcnt, 1 barrier/K-step),
// mid -> LDS sMid (aliases dead sA, 16KB). Phase 2 = R11 gemm2 chunk loop,
// A-frags from sMid, direct scalar epilogue (no sOut). LDS 48.5KB -> 3 blk/CU.

__global__ __launch_bounds__(512, 6) void k_fuse(
    const float* __restrict__ h, const float* __restrict__ b1g,
    const float* __restrict__ b2g, const unsigned short* __restrict__ W1til,
    const unsigned short* __restrict__ W2lin, const int* __restrict__ offsets,
    const int* __restrict__ perm, float* __restrict__ out) {

  __shared__ __align__(16) unsigned short sA[2][4096];   // ph1 A dbuf; ph2: sMid
  __shared__ __align__(16) unsigned short sB[2][8192];   // ph1 W1 dbuf; ph2 W2 dbuf
  __shared__ int sTok[64];

  const int tid = threadIdx.x;
  const int l = tid & 63, w = tid >> 6;
  const int lr = l & 15, lg = l >> 4;
  const int wr = w >> 2, wc = w & 3;        // phase-1 wave tiling
  const int row = tid >> 3, o8 = tid & 7;   // phase-1 A staging

  const int nwg = NTOK / 64 + NUM_CLUSTERS;
  int c, base, nvalid;
  if (!locate(offsets, xcd_swz(blockIdx.x, nwg), 64, c, base, nvalid)) return;

  if (tid < 64) sTok[tid] = perm[base + min(tid, nvalid - 1)];
  LGKM0();
  SBAR();

  const unsigned short* w1base = W1til + (size_t)c * 16 * 8192;
  const unsigned short* wlin   = W2lin + (size_t)c * 131072;
  const float* hrow = h + (long)sTok[row] * HIDDEN + o8 * 8;

  // ---------------- phase 1 ----------------
  float4 vaA[2], vaB[2];
  vaA[0] = *(const float4*)(hrow);       vaA[1] = *(const float4*)(hrow + 4);
  SCB();
  gload16(w1base + tid * 8, &sB[0][tid * 8]);
  gload16(w1base + 4096 + tid * 8, &sB[0][4096 + tid * 8]);
  SCB();
  vaB[0] = *(const float4*)(hrow + 64);  vaB[1] = *(const float4*)(hrow + 68);
  SCB();
  *(bf16x8*)&sA[0][SWZS(row, row * 64 + o8 * 8)] = pack8(vaA[0], vaA[1]);
  LGKM0();
  VMW(2);
  SBAR();

  f32x4 acc[2][2];
  #pragma unroll
  for (int i = 0; i < 2; ++i)
    #pragma unroll
    for (int j = 0; j < 2; ++j) { f32x4 z = {0.f, 0.f, 0.f, 0.f}; acc[i][j] = z; }

#define G1_MFMA(CUR)                                                          \
  do {                                                                        \
    _Pragma("unroll")                                                         \
    for (int kk = 0; kk < 2; ++kk) {                                          \
      bf16x8 af[2], bfr[2];                                                   \
      _Pragma("unroll")                                                       \
      for (int mf = 0; mf < 2; ++mf) {                                        \
        const int m = wr * 32 + mf * 16 + lr;                                 \
        af[mf] = *(const bf16x8*)&sA[CUR][SWZS(m, m * 64 + kk * 32 + lg * 8)];\
      }                                                                       \
      _Pragma("unroll")                                                       \
      for (int nf = 0; nf < 2; ++nf) {                                        \
        const int rn = wc * 32 + nf * 16 + lr;                                \
        bfr[nf] = *(const bf16x8*)&sB[CUR][SWZS(rn, rn * 64 + kk * 32 + lg * 8)]; \
      }                                                                       \
      _Pragma("unroll")                                                       \
      for (int mf = 0; mf < 2; ++mf)                                          \
        _Pragma("unroll")                                                     \
        for (int nf = 0; nf < 2; ++nf)                                        \
          acc[mf][nf] = __builtin_amdgcn_mfma_f32_16x16x32_bf16(              \
              af[mf], bfr[nf], acc[mf][nf], 0, 0, 0);                         \
    }                                                                         \
  } while (0)

  #pragma unroll
  for (int t = 0; t < 16; ++t) {
    const int cur = t & 1;
    if (t < 15) {
      const unsigned short* w1s = w1base + (t + 1) * 8192;
      gload16(w1s + tid * 8, &sB[cur ^ 1][tid * 8]);
      gload16(w1s + 4096 + tid * 8, &sB[cur ^ 1][4096 + tid * 8]);
      SCB();
    }
    if (t < 14) {
      if (t & 1) {
        vaB[0] = *(const float4*)(hrow + (t + 2) * 64);
        vaB[1] = *(const float4*)(hrow + (t + 2) * 64 + 4);
      } else {
        vaA[0] = *(const float4*)(hrow + (t + 2) * 64);
        vaA[1] = *(const float4*)(hrow + (t + 2) * 64 + 4);
      }
      SCB();
    }
    G1_MFMA(cur);
    if (t < 15) {
      const float4* src = ((t + 1) & 1) ? vaB : vaA;
      *(bf16x8*)&sA[cur ^ 1][SWZS(row, row * 64 + o8 * 8)] = pack8(src[0], src[1]);
      if (t < 14) { VMW(2); } else { VMW(0); }
      LGKM0();
      SBAR();
    }
  }
#undef G1_MFMA

  // ---------------- transition: issue ph2 B(0); gelu -> sMid ----------------
  unsigned short* sMid = &sA[0][0];   // 8192 shorts = 16KB, phase-1 sA is dead
  gload16(wlin + tid * 8, &sB[0][tid * 8]);
  gload16(wlin + 4096 + tid * 8, &sB[0][4096 + tid * 8]);
  SCB();
  SBAR();   // all waves' phase-1 LDS reads (sA/sB[1]) complete

  {
    float b1v[2];
    #pragma unroll
    for (int nf = 0; nf < 2; ++nf) b1v[nf] = b1g[c * BOT + wc * 32 + nf * 16 + lr];
    #pragma unroll
    for (int mf = 0; mf < 2; ++mf) {
      #pragma unroll
      for (int nf = 0; nf < 2; ++nf) {
        #pragma unroll
        for (int r = 0; r < 4; ++r) {
          float x = acc[mf][nf][r] + b1v[nf];
          float g = 0.5f * x * (1.0f + erff(x * 0.70710678118654752f));
          const int m = wr * 32 + mf * 16 + lg * 4 + r;
          const int n = wc * 32 + nf * 16 + lr;
          sMid[SWZS(m, m * 128 + n)] = f2bf(g);
        }
      }
    }
  }
  LGKM0();
  VMW(0);   // B(0) landed
  SBAR();   // sMid visible everywhere

  // ---------------- phase 2 ----------------
  const int wrow = (w & 3) * 16;   // wave's 16-token row block
  const int ch = w >> 2;           // col half of each 64-col chunk

  // A fragments from sMid
  bf16x8 ma[4];
  {
    const int mrow = wrow + lr;
    #pragma unroll
    for (int kk = 0; kk < 4; ++kk)
      ma[kk] = *(const bf16x8*)&sMid[SWZS(mrow, mrow * 128 + kk * 32 + lg * 8)];
  }

  // per-lane row pointers (rows lg*4 + r within wave block)
  const float* hr[4];
  float* orp[4];
  #pragma unroll
  for (int r = 0; r < 4; ++r) {
    const long tk = (long)sTok[wrow + lg * 4 + r] * HIDDEN;
    hr[r] = h + tk;
    orp[r] = out + tk;
  }
  const float* b2c = b2g + c * HIDDEN;

  for (int nc = 0; nc < 16; ++nc) {
    const int cur = nc & 1;
    const int cb = nc * 64 + ch * 32;
    // this chunk's residual/bias scalar prefetch (issued BEFORE B(nc+1))
    float hv[2][4], bv[2];
    #pragma unroll
    for (int nf = 0; nf < 2; ++nf)
      #pragma unroll
      for (int r = 0; r < 4; ++r)
        hv[nf][r] = hr[r][cb + nf * 16 + lr];
    #pragma unroll
    for (int nf = 0; nf < 2; ++nf) bv[nf] = b2c[cb + nf * 16 + lr];
    SCB();
    if (nc < 15) {
      const unsigned short* ws2 = wlin + (nc + 1) * 8192;
      gload16(ws2 + tid * 8, &sB[cur ^ 1][tid * 8]);
      gload16(ws2 + 4096 + tid * 8, &sB[cur ^ 1][4096 + tid * 8]);
      SCB();
    }

    f32x4 a2[2];
    { f32x4 z = {0.f, 0.f, 0.f, 0.f}; a2[0] = z; a2[1] = z; }
    #pragma unroll
    for (int kk = 0; kk < 4; ++kk) {
      #pragma unroll
      for (int nf = 0; nf < 2; ++nf) {
        const bf16x8 bf =
            *(const bf16x8*)&sB[cur][(kk * 4 + ch * 2 + nf) * 512 + l * 8];
        a2[nf] = __builtin_amdgcn_mfma_f32_16x16x32_bf16(ma[kk], bf, a2[nf], 0, 0, 0);
      }
    }

    // direct scalar epilogue: per instr = 4 rows x 64B contiguous segments.
    // Unconditional clamped stores (rows >= nvalid duplicate row nvalid-1).
    #pragma unroll
    for (int nf = 0; nf < 2; ++nf) {
      #pragma unroll
      for (int r = 0; r < 4; ++r) {
        orp[r][cb + nf * 16 + lr] = a2[nf][r] + hv[nf][r] + bv[nf];
      }
    }
    if (nc < 15) {
      VMW(8);   // drain B(nc+1); the 8 stores stay in flight
      SBAR();   // everyone done with sB[cur]
    }
  }
}

// ---------------- fallback fused kernel (ws too small): TM=128 ----------------
#define FSWZ(row, sidx) ((sidx) ^ (((row) & 7) << 3))

__global__ __launch_bounds__(256, 2) void k_fused(
    const float* __restrict__ h, const float* __restrict__ b1g,
    const float* __restrict__ b2g, const unsigned short* __restrict__ W1til,
    const unsigned short* __restrict__ W2til, const int* __restrict__ offsets,
    const int* __restrict__ perm, float* __restrict__ out) {

  __shared__ __align__(16) unsigned short sAB[16384];
  __shared__ __align__(16) unsigned short sMid[16384];
  __shared__ int sTok[128];

  const int tid = threadIdx.x;
  const int l = tid & 63, w = tid >> 6;
  const int wr = w >> 1, wc = w & 1;
  const int lr = l & 15, lg = l >> 4;

  int c, base, nvalid;
  if (!locate(offsets, blockIdx.x, 128, c, base, nvalid)) return;

  if (tid < 128) sTok[tid] = perm[base + min(tid, nvalid - 1)];
  __syncthreads();

  const unsigned short* w1base = W1til + (size_t)c * 16 * 8192;
  const unsigned short* w2base = W2til + (size_t)c * 16 * 8192;

  const int arow = tid >> 1, ahalf = tid & 1;
  const long htok = (long)sTok[arow] * HIDDEN;

  f32x4 acc[4][4];
  #pragma unroll
  for (int i = 0; i < 4; ++i)
    #pragma unroll
    for (int j = 0; j < 4; ++j) { f32x4 z = {0.f, 0.f, 0.f, 0.f}; acc[i][j] = z; }

  for (int ks = 0; ks < 16; ++ks) {
    __syncthreads();
    const unsigned short* w1s = w1base + ks * 8192;
    #pragma unroll
    for (int j = 0; j < 4; ++j)
      gload16(w1s + j * 2048 + tid * 8, &sAB[8192 + j * 2048 + tid * 8]);
    {
      const float* hp = h + htok + ks * 64 + ahalf * 32;
      float4 v0 = *(const float4*)(hp + 0),  v1 = *(const float4*)(hp + 4);
      float4 v2 = *(const float4*)(hp + 8),  v3 = *(const float4*)(hp + 12);
      float4 v4 = *(const float4*)(hp + 16), v5 = *(const float4*)(hp + 20);
      float4 v6 = *(const float4*)(hp + 24), v7 = *(const float4*)(hp + 28);
      const int sb = arow * 64 + ahalf * 32;
      *(bf16x8*)&sAB[FSWZ(arow, sb + 0)]  = pack8(v0, v1);
      *(bf16x8*)&sAB[FSWZ(arow, sb + 8)]  = pack8(v2, v3);
      *(bf16x8*)&sAB[FSWZ(arow, sb + 16)] = pack8(v4, v5);
      *(bf16x8*)&sAB[FSWZ(arow, sb + 24)] = pack8(v6, v7);
    }
    __syncthreads();
    #pragma unroll
    for (int kk = 0; kk < 2; ++kk) {
      bf16x8 af[4], bfr[4];
      #pragma unroll
      for (int mf = 0; mf < 4; ++mf) {
        const int rw = wr * 64 + mf * 16 + lr;
        af[mf] = *(const bf16x8*)&sAB[FSWZ(rw, rw * 64 + kk * 32 + lg * 8)];
      }
      #pragma unroll
      for (int nf = 0; nf < 4; ++nf) {
        const int rn = wc * 64 + nf * 16 + lr;
        bfr[nf] = *(const bf16x8*)&sAB[8192 + FSWZ(rn, rn * 64 + kk * 32 + lg * 8)];
      }
      #pragma unroll
      for (int mf = 0; mf < 4; ++mf)
        #pragma unroll
        for (int nf = 0; nf < 4; ++nf)
          acc[mf][nf] = __builtin_amdgcn_mfma_f32_16x16x32_bf16(af[mf], bfr[nf], acc[mf][nf], 0, 0, 0);
    }
  }

  float b1v[4];
  #pragma unroll
  for (int nf = 0; nf < 4; ++nf) b1v[nf] = b1g[c * BOT + wc * 64 + nf * 16 + lr];
  #pragma unroll
  for (int mf = 0; mf < 4; ++mf)
    #pragma unroll
    for (int nf = 0; nf < 4; ++nf)
      #pragma unroll
      for (int r = 0; r < 4; ++r) {
        float x = acc[mf][nf][r] + b1v[nf];
        float g = 0.5f * x * (1.0f + erff(x * 0.70710678118654752f));
        const int m = wr * 64 + mf * 16 + lg * 4 + r;
        const int n = wc * 64 + nf * 16 + lr;
        sMid[FSWZ(m, m * 128 + n)] = f2bf(g);
      }

  for (int nc = 0; nc < 16; ++nc) {
    __syncthreads();
    #pragma unroll
    for (int j = 0; j < 4; ++j)
      gload16(w2base + nc * 8192 + j * 2048 + tid * 8, &sAB[j * 2048 + tid * 8]);
    __syncthreads();

    f32x4 a2[4][2];
    #pragma unroll
    for (int i = 0; i < 4; ++i)
      #pragma unroll
      for (int j = 0; j < 2; ++j) { f32x4 z = {0.f, 0.f, 0.f, 0.f}; a2[i][j] = z; }

    #pragma unroll
    for (int kk = 0; kk < 4; ++kk) {
      bf16x8 af[4], bfr[2];
      #pragma unroll
      for (int mf = 0; mf < 4; ++mf) {
        const int m = wr * 64 + mf * 16 + lr;
        af[mf] = *(const bf16x8*)&sMid[FSWZ(m, m * 128 + kk * 32 + lg * 8)];
      }
      #pragma unroll
      for (int nf = 0; nf < 2; ++nf) {
        const int rn = wc * 32 + nf * 16 + lr;
        bfr[nf] = *(const bf16x8*)&sAB[FSWZ(rn, rn * 128 + kk * 32 + lg * 8)];
      }
      #pragma unroll
      for (int mf = 0; mf < 4; ++mf)
        #pragma unroll
        for (int nf = 0; nf < 2; ++nf)
          a2[mf][nf] = __builtin_amdgcn_mfma_f32_16x16x32_bf16(af[mf], bfr[nf], a2[mf][nf], 0, 0, 0);
    }

    #pragma unroll
    for (int nf = 0; nf < 2; ++nf) {
      const int nn = nc * 64 + wc * 32 + nf * 16 + lr;
      const float b2v = b2g[c * HIDDEN + nn];
      #pragma unroll
      for (int mf = 0; mf < 4; ++mf)
        #pragma unroll
        for (int r = 0; r < 4; ++r) {
          const int m = wr * 64 + mf * 16 + lg * 4 + r;
          if (m < nvalid) {
            const long tk = (long)sTok[m] * HIDDEN;
            out[tk + nn] = h[tk + nn] + a2[mf][nf][r] + b2v;
          }
        }
    }
  }
}

// ---------------- launcher ----------------
extern "C" void kernel_launch(void* const* d_in, const int* in_sizes, int n_in,
                              void* d_out, int out_size, void* d_ws, size_t ws_size,
                              hipStream_t stream) {
  const float* h   = (const float*)d_in[0];
  const int*   ids = (const int*)d_in[1];
  const float* W1  = (const float*)d_in[2];
  const float* b1  = (const float*)d_in[3];
  const float* W2  = (const float*)d_in[4];
  const float* b2  = (const float*)d_in[5];
  float* out = (float*)d_out;

  char* ws = (char*)d_ws;
  int* counts  = (int*)ws;            // 16 ints
  int* cursor  = (int*)(ws + 64);     // 16 ints
  int* offsets = (int*)(ws + 128);    // 17 ints
  int* perm    = (int*)(ws + 256);    // 65536 ints, ends at 262400
  unsigned short* W1til = (unsigned short*)(ws + 262400);             // 4 MB
  unsigned short* W2buf = W1til + (size_t)16 * 16 * 8192;             // 4 MB (lin or til)
  const size_t need = 262400 + 2 * (size_t)16 * 16 * 8192 * 2;

  k_zero<<<1, 64, 0, stream>>>(counts);
  k_hist<<<256, 256, 0, stream>>>(ids, counts);
  k_scan<<<1, 64, 0, stream>>>(counts, offsets, cursor);
  k_scatter<<<NTOK / 256, 256, 0, stream>>>(ids, cursor, perm);
  k_w1til<<<1024, 256, 0, stream>>>(W1, W1til);

  if (ws_size >= need) {
    k_w2lin<<<1024, 256, 0, stream>>>(W2, W2buf);
    const int nwg = NTOK / 64 + NUM_CLUSTERS;
    k_fuse<<<nwg, 512, 0, stream>>>(h, b1, b2, W1til, W2buf, offsets, perm, out);
  } else {
    k_w2til<<<1024, 256, 0, stream>>>(W2, W2buf);
    k_fused<<<NTOK / 128 + NUM_CLUSTERS, 256, 0, stream>>>(
        h, b1, b2, W1til, W2buf, offsets, perm, out);
  }
}